// Round 2
// baseline (13420.322 us; speedup 1.0000x reference)
//
#include <hip/hip_runtime.h>
#include <hip/hip_bf16.h>
#include <cstdint>

typedef __hip_bfloat16 bf16;
typedef __attribute__((ext_vector_type(8))) short bf16x8v;   // 8 bf16 in 4 VGPRs
typedef __attribute__((ext_vector_type(4))) float f32x4;

#define TM1 64
#define BATCH 512
#define BELIEF 2048
#define STATE 256
#define ACTION 64
#define HIDDEN 2048
#define EMB 1024

// output offsets (elements) in d_out, per reference return order
#define OUT_BEL  ((size_t)0)
#define OUT_PST  ((size_t)67108864)   // prior_states
#define OUT_PMU  ((size_t)75497472)   // prior_means
#define OUT_PSD  ((size_t)83886080)   // prior_std_devs
#define OUT_QST  ((size_t)92274688)   // posterior_states
#define OUT_QMU  ((size_t)100663296)  // posterior_means
#define OUT_QSD  ((size_t)109051904)  // posterior_std_devs

__device__ __forceinline__ void gload_lds16(const bf16* g, bf16* l) {
  __builtin_amdgcn_global_load_lds(
      (const __attribute__((address_space(1))) unsigned int*)g,
      (__attribute__((address_space(3))) unsigned int*)l, 16, 0, 0);
}

__device__ __forceinline__ unsigned short bfb(float f) {
  bf16 h = __float2bfloat16(f);
  return *reinterpret_cast<unsigned short*>(&h);
}

struct GDesc {
  const bf16* A; const bf16* B; const float* bias; void* C;
  int M, N, K, ksplit, mode, nb;
  // mode 0: C fp32 (+bias). mode 1: C bf16 relu (+bias).
  // mode 3: split-K fp32 partials (no bias) + ticket-reduced posterior epilogue.
};
struct PostArgs {
  const float* eps; float* o_mu; float* o_sd; float* o_st;
  const float* nt_next; const float* act_next; bf16* xcat;
  unsigned* counters; int make_xcat;
};

// ---------------------------------------------------------------------------
// multi-GEMM: up to 3 descs per launch. C[M,N] = A[M,K] @ B[N,K]^T (+bias)
// grid-wide bijective XCD swizzle; per-desc decode with m fastest (B-panel
// sharing blocks land on the same XCD chunk).
// ---------------------------------------------------------------------------
template<int BM, int BN>
__global__ __launch_bounds__(256)
void gemm_multi(GDesc d0, GDesc d1, GDesc d2, PostArgs pa)
{
  const int nwg = gridDim.x;
  const int orig = blockIdx.x;
  const int q8 = nwg >> 3, r8 = nwg & 7;
  const int xcd = orig & 7, oo = orig >> 3;
  int bid = (xcd < r8 ? xcd * (q8 + 1) : r8 * (q8 + 1) + (xcd - r8) * q8) + oo;

  GDesc d = d0;
  if (bid >= d.nb) { bid -= d.nb; d = d1; if (bid >= d.nb) { bid -= d.nb; d = d2; } }

  const int nm = d.M / BM;
  const int per = nm * (d.N / BN);
  const int ks  = bid / per;
  const int rem = bid - ks * per;
  const int mb  = rem % nm;
  const int nbk = rem / nm;
  const int m0 = mb * BM, n0 = nbk * BN;
  const int Kc = d.K / d.ksplit;
  const int kbeg = ks * Kc, kend = kbeg + Kc;

  __shared__ __align__(16) bf16 sA[BM * 64];
  __shared__ __align__(16) bf16 sB[BN * 64];

  const int tid = threadIdx.x;
  const int lane = tid & 63;
  const int wid = tid >> 6;
  const int wm = wid >> 1, wn = wid & 1;
  const int lr = lane & 15;
  const int ko = (lane >> 4) * 8;
  constexpr int WMt = BM / 2, WNt = BN / 2;
  constexpr int MR = WMt / 16, NR = WNt / 16;

  f32x4 acc[MR][NR] = {};

  const bf16* Abase = d.A + (size_t)m0 * d.K;
  const bf16* Bbase = d.B + (size_t)n0 * d.K;

  for (int k0 = kbeg; k0 < kend; k0 += 64) {
    __syncthreads();
    #pragma unroll
    for (int i = 0; i < BM / 32; ++i) {
      int c = i * 256 + tid;
      int row = c >> 3, kc = (c & 7) * 8;
      gload_lds16(Abase + (size_t)row * d.K + k0 + kc, &sA[c * 8]);
    }
    #pragma unroll
    for (int i = 0; i < BN / 32; ++i) {
      int c = i * 256 + tid;
      int row = c >> 3, kc = (c & 7) * 8;
      gload_lds16(Bbase + (size_t)row * d.K + k0 + kc, &sB[c * 8]);
    }
    __syncthreads();

    #pragma unroll
    for (int kk = 0; kk < 2; ++kk) {
      bf16x8v af[MR], bfv[NR];
      #pragma unroll
      for (int m = 0; m < MR; ++m)
        af[m] = *(const bf16x8v*)&sA[(wm * WMt + m * 16 + lr) * 64 + kk * 32 + ko];
      #pragma unroll
      for (int n = 0; n < NR; ++n)
        bfv[n] = *(const bf16x8v*)&sB[(wn * WNt + n * 16 + lr) * 64 + kk * 32 + ko];
      #pragma unroll
      for (int m = 0; m < MR; ++m)
        #pragma unroll
        for (int n = 0; n < NR; ++n)
          acc[m][n] = __builtin_amdgcn_mfma_f32_16x16x32_bf16(af[m], bfv[n], acc[m][n], 0, 0, 0);
    }
  }

  const int r0 = (lane >> 4) * 4;
  if (d.mode != 3) {
    #pragma unroll
    for (int m = 0; m < MR; ++m) {
      #pragma unroll
      for (int n = 0; n < NR; ++n) {
        int gc = n0 + wn * WNt + n * 16 + lr;
        float bv = d.bias[gc];
        #pragma unroll
        for (int r = 0; r < 4; ++r) {
          int gr = m0 + wm * WMt + m * 16 + r0 + r;
          float v = acc[m][n][r] + bv;
          if (d.mode == 1)
            ((bf16*)d.C)[(size_t)gr * d.N + gc] = __float2bfloat16(v > 0.f ? v : 0.f);
          else
            ((float*)d.C)[(size_t)gr * d.N + gc] = v;
        }
      }
    }
  } else {
    // split-K partial store (no bias)
    float* P = (float*)d.C + (size_t)ks * d.M * d.N;
    #pragma unroll
    for (int m = 0; m < MR; ++m)
      #pragma unroll
      for (int n = 0; n < NR; ++n) {
        int gc = n0 + wn * WNt + n * 16 + lr;
        #pragma unroll
        for (int r = 0; r < 4; ++r) {
          int gr = m0 + wm * WMt + m * 16 + r0 + r;
          P[(size_t)gr * d.N + gc] = acc[m][n][r];
        }
      }
    __threadfence();
    __syncthreads();
    __shared__ unsigned tic;
    const int pair = mb * 4 + (nbk & 3);
    if (tid == 0) tic = atomicAdd(&pa.counters[pair], 1u);
    __syncthreads();
    if (tic == 7) {
      __threadfence();   // acquire: see all 8 contributors' partials
      const int nl = nbk & 3;
      const float* Y = (const float*)d.C;
      for (int e = tid; e < 64 * 64; e += 256) {
        int rr = e >> 6, cc = e & 63;
        int b = m0 + rr;
        int j = nl * 64 + cc;
        float loc = d.bias[j], raw = d.bias[256 + j];
        #pragma unroll
        for (int k2 = 0; k2 < 4; ++k2) {
          loc += Y[(size_t)k2 * 262144 + (size_t)b * 512 + j];
          raw += Y[(size_t)k2 * 262144 + (size_t)b * 512 + 256 + j];
        }
        float sp = (raw > 20.f) ? raw : log1pf(__expf(raw));
        float scale = sp + 0.1f;
        float st = loc + scale * pa.eps[b * 256 + j];
        pa.o_mu[b * 256 + j] = loc;
        pa.o_sd[b * 256 + j] = scale;
        pa.o_st[b * 256 + j] = st;
        if (pa.make_xcat)
          pa.xcat[b * 320 + j] = __float2bfloat16(st * pa.nt_next[b]);
      }
      if (pa.make_xcat && nl == 0) {
        for (int e = tid; e < 64 * 64; e += 256) {
          int rr = e >> 6, cc = e & 63;
          int b = m0 + rr;
          pa.xcat[b * 320 + 256 + cc] = __float2bfloat16(pa.act_next[b * 64 + cc]);
        }
      }
    }
  }
}

// ---------------------------------------------------------------------------
__global__ void transpose_cvt(const float* __restrict__ src, bf16* __restrict__ dst,
                              int K, int N)
{
  __shared__ float t[32][33];
  int n0 = blockIdx.x * 32, k0 = blockIdx.y * 32;
  int tx = threadIdx.x, ty = threadIdx.y;
  #pragma unroll
  for (int i = 0; i < 32; i += 8)
    t[ty + i][tx] = src[(size_t)(k0 + ty + i) * N + n0 + tx];
  __syncthreads();
  #pragma unroll
  for (int i = 0; i < 32; i += 8)
    dst[(size_t)(n0 + ty + i) * K + k0 + tx] = __float2bfloat16(t[tx][ty + i]);
}

__global__ void init_belief(const float* __restrict__ prev_belief,
                            float* __restrict__ bf32, bf16* __restrict__ bb16)
{
  int i = blockIdx.x * 256 + threadIdx.x;
  float v = prev_belief[i];
  bf32[i] = v;
  bb16[i] = __float2bfloat16(v);
}

__global__ void xcat0_kernel(const float* __restrict__ prev_state,
                             const float* __restrict__ nt0,
                             const float* __restrict__ act0,
                             bf16* __restrict__ xcat)
{
  int idx = blockIdx.x * 256 + threadIdx.x;
  if (idx >= BATCH * (STATE + ACTION)) return;
  int b = idx / (STATE + ACTION);
  int c = idx - b * (STATE + ACTION);
  float v;
  if (c < STATE) v = prev_state[b * STATE + c] * nt0[b];
  else           v = act0[b * ACTION + (c - STATE)];
  xcat[idx] = __float2bfloat16(v);
}

__device__ __forceinline__ float sigmoidf_(float x) { return 1.f / (1.f + __expf(-x)); }

__device__ __forceinline__ float gru1(float ir, float hr, float iz, float hz,
                                      float in_, float hn, float bo)
{
  float r = sigmoidf_(ir + hr);
  float z = sigmoidf_(iz + hz);
  float n = tanhf(in_ + r * hn);
  return (1.f - z) * n + z * bo;
}

// GRU gates (vec4) + belief carry + bf16 roll slot + hqcat assembly + counter zero
__global__ void gru_ew(const float* __restrict__ gi, const float* __restrict__ gh,
                       float* __restrict__ belief, float* __restrict__ out_bel,
                       bf16* __restrict__ roll_slot, bf16* __restrict__ hqcat,
                       const float* __restrict__ obs_t, unsigned* __restrict__ counters)
{
  int tid = threadIdx.x;
  if (blockIdx.x == 0 && tid < 32) counters[tid] = 0;
  int i = blockIdx.x * 256 + tid;          // float4 index over 512*2048/4
  int b = i >> 9;
  int c = (i & 511) * 4;
  size_t gb = (size_t)b * 6144;
  float4 ir = *(const float4*)&gi[gb + c];
  float4 iz = *(const float4*)&gi[gb + 2048 + c];
  float4 in_ = *(const float4*)&gi[gb + 4096 + c];
  float4 hr = *(const float4*)&gh[gb + c];
  float4 hz = *(const float4*)&gh[gb + 2048 + c];
  float4 hn = *(const float4*)&gh[gb + 4096 + c];
  float4 bo = *(const float4*)&belief[(size_t)b * 2048 + c];
  float4 nb;
  nb.x = gru1(ir.x, hr.x, iz.x, hz.x, in_.x, hn.x, bo.x);
  nb.y = gru1(ir.y, hr.y, iz.y, hz.y, in_.y, hn.y, bo.y);
  nb.z = gru1(ir.z, hr.z, iz.z, hz.z, in_.z, hn.z, bo.z);
  nb.w = gru1(ir.w, hr.w, iz.w, hz.w, in_.w, hn.w, bo.w);
  *(float4*)&belief[(size_t)b * 2048 + c] = nb;
  *(float4*)&out_bel[(size_t)b * 2048 + c] = nb;
  ushort4 u; u.x = bfb(nb.x); u.y = bfb(nb.y); u.z = bfb(nb.z); u.w = bfb(nb.w);
  *(ushort4*)&roll_slot[(size_t)b * 2048 + c] = u;
  *(ushort4*)&hqcat[(size_t)b * 3072 + c] = u;
  if ((i & 511) < 256) {
    float4 ov = *(const float4*)&obs_t[(size_t)b * 1024 + c];
    ushort4 uo; uo.x = bfb(ov.x); uo.y = bfb(ov.y); uo.z = bfb(ov.z); uo.w = bfb(ov.w);
    *(ushort4*)&hqcat[(size_t)b * 3072 + 2048 + c] = uo;
  }
}

__global__ void prior_ew(const float* __restrict__ yp, const float* __restrict__ eps,
                         float* __restrict__ o_mu, float* __restrict__ o_sd,
                         float* __restrict__ o_st)
{
  int idx = blockIdx.x * 256 + threadIdx.x;   // 4096*256
  int r = idx >> 8;
  int j = idx & 255;
  float loc = yp[(size_t)r * 512 + j];
  float raw = yp[(size_t)r * 512 + 256 + j];
  float sp = (raw > 20.f) ? raw : log1pf(__expf(raw));
  float scale = sp + 0.1f;
  o_mu[idx] = loc;
  o_sd[idx] = scale;
  o_st[idx] = loc + scale * eps[idx];
}

// ---------------------------------------------------------------------------
extern "C" void kernel_launch(void* const* d_in, const int* in_sizes, int n_in,
                              void* d_out, int out_size, void* d_ws, size_t ws_size,
                              hipStream_t stream)
{
  (void)in_sizes; (void)n_in; (void)out_size; (void)ws_size;
  const float* prev_state = (const float*)d_in[0];
  const float* actions    = (const float*)d_in[1];
  const float* prev_belief= (const float*)d_in[2];
  const float* obs_emb    = (const float*)d_in[3];
  const float* nonterm    = (const float*)d_in[4];
  const float* W_embed    = (const float*)d_in[5];
  const float* b_embed    = (const float*)d_in[6];
  const float* Wi         = (const float*)d_in[7];
  const float* bi         = (const float*)d_in[8];
  const float* Wh         = (const float*)d_in[9];
  const float* bh         = (const float*)d_in[10];
  const float* W1         = (const float*)d_in[11];
  const float* b1         = (const float*)d_in[12];
  const float* W2         = (const float*)d_in[13];
  const float* b2         = (const float*)d_in[14];
  const float* W1p        = (const float*)d_in[15];
  const float* b1p        = (const float*)d_in[16];
  const float* W2p        = (const float*)d_in[17];
  const float* b2p        = (const float*)d_in[18];
  const float* eps_p      = (const float*)d_in[19];
  const float* eps_q      = (const float*)d_in[20];
  float* out = (float*)d_out;

  char* ws = (char*)d_ws;
  size_t off = 0;
  auto alloc = [&](size_t bytes) -> char* {
    char* p = ws + off;
    off = (off + bytes + 255) & ~(size_t)255;
    return p;
  };
  bf16* WembT = (bf16*)alloc((size_t)2048 * 320 * 2);
  bf16* WiT   = (bf16*)alloc((size_t)6144 * 2048 * 2);
  bf16* WhT   = (bf16*)alloc((size_t)6144 * 2048 * 2);
  bf16* W1T   = (bf16*)alloc((size_t)2048 * 2048 * 2);
  bf16* W2T   = (bf16*)alloc((size_t)512 * 2048 * 2);
  bf16* W1pT  = (bf16*)alloc((size_t)2048 * 3072 * 2);
  bf16* W2pT  = (bf16*)alloc((size_t)512 * 2048 * 2);
  float* belief_f32 = (float*)alloc((size_t)BATCH * BELIEF * 4);
  bf16*  bel_init   = (bf16*)alloc((size_t)BATCH * BELIEF * 2);
  bf16*  roll       = (bf16*)alloc((size_t)8 * BATCH * BELIEF * 2);   // bf16 beliefs, 8 steps
  bf16*  xcat       = (bf16*)alloc((size_t)BATCH * 320 * 2);
  bf16*  hidden     = (bf16*)alloc((size_t)BATCH * BELIEF * 2);
  float* gi         = (float*)alloc((size_t)BATCH * 3 * BELIEF * 4);
  float* gh         = (float*)alloc((size_t)BATCH * 3 * BELIEF * 4);
  bf16*  hqcat      = (bf16*)alloc((size_t)BATCH * 3072 * 2);
  bf16*  hq         = (bf16*)alloc((size_t)BATCH * HIDDEN * 2);
  float* yqp        = (float*)alloc((size_t)4 * 512 * 512 * 4);
  bf16*  hp         = (bf16*)alloc((size_t)4096 * HIDDEN * 2);
  float* yp         = (float*)alloc((size_t)4096 * 512 * 4);
  unsigned* counters= (unsigned*)alloc(32 * 4);

  auto mk = [](const bf16* A, const bf16* B, const float* bias, void* C,
               int M, int N, int K, int ksplit, int mode, int BM, int BN) {
    GDesc g; g.A = A; g.B = B; g.bias = bias; g.C = C;
    g.M = M; g.N = N; g.K = K; g.ksplit = ksplit; g.mode = mode;
    g.nb = (M / BM) * (N / BN) * ksplit;
    return g;
  };
  GDesc dz128 = mk(nullptr, nullptr, nullptr, nullptr, 128, 128, 64, 1, 0, 128, 128); dz128.nb = 0;
  GDesc dz64  = mk(nullptr, nullptr, nullptr, nullptr, 64, 64, 64, 1, 0, 64, 64);     dz64.nb = 0;
  PostArgs pz{}; pz.counters = counters;

  dim3 tb(32, 8);
  transpose_cvt<<<dim3(2048/32, 320/32),  tb, 0, stream>>>(W_embed, WembT, 320, 2048);
  transpose_cvt<<<dim3(6144/32, 2048/32), tb, 0, stream>>>(Wi, WiT, 2048, 6144);
  transpose_cvt<<<dim3(6144/32, 2048/32), tb, 0, stream>>>(Wh, WhT, 2048, 6144);
  transpose_cvt<<<dim3(2048/32, 2048/32), tb, 0, stream>>>(W1, W1T, 2048, 2048);
  transpose_cvt<<<dim3(512/32, 2048/32),  tb, 0, stream>>>(W2, W2T, 2048, 512);
  transpose_cvt<<<dim3(2048/32, 3072/32), tb, 0, stream>>>(W1p, W1pT, 3072, 2048);
  transpose_cvt<<<dim3(512/32, 2048/32),  tb, 0, stream>>>(W2p, W2pT, 2048, 512);

  init_belief<<<(BATCH * BELIEF) / 256, 256, 0, stream>>>(prev_belief, belief_f32, bel_init);
  xcat0_kernel<<<(BATCH * 320 + 255) / 256, 256, 0, stream>>>(prev_state, nonterm, actions, xcat);

  { // hidden_0 = relu(xcat0 @ W_embed)
    GDesc e = mk(xcat, WembT, b_embed, hidden, 512, 2048, 320, 1, 1, 64, 64);
    gemm_multi<64,64><<<e.nb, 256, 0, stream>>>(e, dz64, dz64, pz);
  }
  { // gh_0 = bel_init @ Wh + bh
    GDesc g = mk(bel_init, WhT, bh, gh, 512, 6144, 2048, 1, 0, 128, 128);
    gemm_multi<128,128><<<g.nb, 256, 0, stream>>>(g, dz128, dz128, pz);
  }

  for (int t = 0; t < TM1; ++t) {
    const bool pr = (t > 0 && (t & 7) == 0);   // fold prior chunk (t/8 - 1)
    // ---- MG_A: gi = hidden @ Wi (+ prior hp GEMM every 8th step) ----
    GDesc a0 = mk(hidden, WiT, bi, gi, 512, 6144, 2048, 1, 0, 128, 128);
    GDesc a1 = pr ? mk(roll, W1T, b1, hp, 4096, 2048, 2048, 1, 1, 128, 128) : dz128;
    gemm_multi<128,128><<<a0.nb + a1.nb, 256, 0, stream>>>(a0, a1, dz128, pz);

    // ---- GRU gates + hqcat + roll slot + counter zero ----
    gru_ew<<<1024, 256, 0, stream>>>(
        gi, gh, belief_f32,
        out + OUT_BEL + (size_t)t * BATCH * BELIEF,
        roll + (size_t)(t & 7) * BATCH * BELIEF,
        hqcat, obs_emb + (size_t)t * BATCH * EMB, counters);

    // ---- MG_B: hq = relu(hqcat @ W1p) ; gh_{t+1} = belief @ Wh ----
    GDesc b0 = mk(hqcat, W1pT, b1p, hq, 512, 2048, 3072, 1, 1, 128, 128);
    GDesc b1d = (t < TM1 - 1)
        ? mk(roll + (size_t)(t & 7) * BATCH * BELIEF, WhT, bh, gh, 512, 6144, 2048, 1, 0, 128, 128)
        : dz128;
    gemm_multi<128,128><<<b0.nb + b1d.nb, 256, 0, stream>>>(b0, b1d, dz128, pz);

    // ---- MG_C: yq split-K4 + fused posterior epilogue (+ prior yp GEMM) ----
    GDesc c0 = mk(hq, W2pT, b2p, yqp, 512, 512, 2048, 4, 3, 64, 64);
    GDesc c1 = pr ? mk(hp, W2T, b2, yp, 4096, 512, 2048, 1, 0, 64, 64) : dz64;
    PostArgs pa;
    pa.eps = eps_q + (size_t)t * BATCH * STATE;
    pa.o_mu = out + OUT_QMU + (size_t)t * BATCH * STATE;
    pa.o_sd = out + OUT_QSD + (size_t)t * BATCH * STATE;
    pa.o_st = out + OUT_QST + (size_t)t * BATCH * STATE;
    int tn = (t < TM1 - 1) ? t + 1 : t;   // t=63 pointers valid but unused
    pa.nt_next  = nonterm + (size_t)tn * BATCH;
    pa.act_next = actions + (size_t)tn * BATCH * ACTION;
    pa.xcat = xcat; pa.counters = counters; pa.make_xcat = (t < TM1 - 1) ? 1 : 0;
    gemm_multi<64,64><<<c0.nb + c1.nb, 256, 0, stream>>>(c0, c1, dz64, pa);

    if (pr) {
      int c = (t >> 3) - 1;
      prior_ew<<<4096, 256, 0, stream>>>(
          yp, eps_p + (size_t)c * 4096 * STATE,
          out + OUT_PMU + (size_t)c * 4096 * STATE,
          out + OUT_PSD + (size_t)c * 4096 * STATE,
          out + OUT_PST + (size_t)c * 4096 * STATE);
    }
    if (t < TM1 - 1) { // hidden_{t+1} = relu(xcat @ W_embed)
      GDesc e = mk(xcat, WembT, b_embed, hidden, 512, 2048, 320, 1, 1, 64, 64);
      gemm_multi<64,64><<<e.nb, 256, 0, stream>>>(e, dz64, dz64, pz);
    }
  }

  // tail: prior chunk 7 (steps 56..63 still in roll)
  {
    GDesc p1 = mk(roll, W1T, b1, hp, 4096, 2048, 2048, 1, 1, 128, 128);
    gemm_multi<128,128><<<p1.nb, 256, 0, stream>>>(p1, dz128, dz128, pz);
    GDesc p2 = mk(hp, W2T, b2, yp, 4096, 512, 2048, 1, 0, 64, 64);
    gemm_multi<64,64><<<p2.nb, 256, 0, stream>>>(p2, dz64, dz64, pz);
    prior_ew<<<4096, 256, 0, stream>>>(
        yp, eps_p + (size_t)7 * 4096 * STATE,
        out + OUT_PMU + (size_t)7 * 4096 * STATE,
        out + OUT_PSD + (size_t)7 * 4096 * STATE,
        out + OUT_PST + (size_t)7 * 4096 * STATE);
  }
}

// Round 3
// 10019.285 us; speedup vs baseline: 1.3394x; 1.3394x over previous
//
#include <hip/hip_runtime.h>
#include <hip/hip_bf16.h>
#include <cstdint>

typedef __hip_bfloat16 bf16;
typedef __attribute__((ext_vector_type(8))) short bf16x8v;   // 8 bf16 in 4 VGPRs
typedef __attribute__((ext_vector_type(4))) float f32x4;

#define TM1 64
#define BATCH 512
#define BELIEF 2048
#define STATE 256
#define ACTION 64
#define HIDDEN 2048
#define EMB 1024

// output offsets (elements) in d_out, per reference return order
#define OUT_BEL  ((size_t)0)
#define OUT_PST  ((size_t)67108864)   // prior_states
#define OUT_PMU  ((size_t)75497472)   // prior_means
#define OUT_PSD  ((size_t)83886080)   // prior_std_devs
#define OUT_QST  ((size_t)92274688)   // posterior_states
#define OUT_QMU  ((size_t)100663296)  // posterior_means
#define OUT_QSD  ((size_t)109051904)  // posterior_std_devs

__device__ __forceinline__ void gload_lds16(const bf16* g, bf16* l) {
  __builtin_amdgcn_global_load_lds(
      (const __attribute__((address_space(1))) unsigned int*)g,
      (__attribute__((address_space(3))) unsigned int*)l, 16, 0, 0);
}

__device__ __forceinline__ unsigned short bfb(float f) {
  bf16 h = __float2bfloat16(f);
  return *reinterpret_cast<unsigned short*>(&h);
}

struct GDesc {
  const bf16* A; const bf16* B; const float* bias; void* C;
  int M, N, K, mode, nb;   // mode 0: C fp32 (+bias). mode 1: C bf16 relu (+bias).
};

// ---------------------------------------------------------------------------
// 2-desc GEMM, T3 "minimum 2-phase" schedule: explicit LDS double-buffer,
// STAGE(t+1) issued BEFORE compute(t), ONE __syncthreads per K-iter.
// C[M,N] = A[M,K](bf16,row) @ B[N,K](bf16,row)^T + bias[N]
// ---------------------------------------------------------------------------
template<int BM, int BN>
__global__ __launch_bounds__(256)
void gemm2(GDesc d0, GDesc d1)
{
  // bijective XCD swizzle (m204)
  const int nwg = gridDim.x;
  const int orig = blockIdx.x;
  const int q8 = nwg >> 3, r8 = nwg & 7;
  const int xcd = orig & 7, oo = orig >> 3;
  int bid = (xcd < r8 ? xcd * (q8 + 1) : r8 * (q8 + 1) + (xcd - r8) * q8) + oo;

  GDesc d = d0;
  if (bid >= d.nb) { bid -= d.nb; d = d1; }

  const int nm = d.M / BM;
  const int mb = bid % nm;
  const int nbk = bid / nm;          // m-fastest: same-B blocks adjacent
  const int m0 = mb * BM, n0 = nbk * BN;

  __shared__ __align__(16) bf16 sA[2][BM * 64];
  __shared__ __align__(16) bf16 sB[2][BN * 64];

  const int tid = threadIdx.x;
  const int lane = tid & 63;
  const int wid = tid >> 6;
  const int wm = wid >> 1, wn = wid & 1;
  const int lr = lane & 15;
  const int ko = (lane >> 4) * 8;
  constexpr int WMt = BM / 2, WNt = BN / 2;
  constexpr int MR = WMt / 16, NR = WNt / 16;

  const bf16* Abase = d.A + (size_t)m0 * d.K;
  const bf16* Bbase = d.B + (size_t)n0 * d.K;
  const int K = d.K;

  auto stage = [&](int buf, int k0) {
    #pragma unroll
    for (int i = 0; i < BM / 32; ++i) {
      int c = i * 256 + tid;
      gload_lds16(Abase + (size_t)(c >> 3) * K + k0 + (c & 7) * 8, &sA[buf][c * 8]);
    }
    #pragma unroll
    for (int i = 0; i < BN / 32; ++i) {
      int c = i * 256 + tid;
      gload_lds16(Bbase + (size_t)(c >> 3) * K + k0 + (c & 7) * 8, &sB[buf][c * 8]);
    }
  };

  f32x4 acc[MR][NR] = {};

  stage(0, 0);
  __syncthreads();                         // drain prologue stage
  const int nk = K >> 6;
  for (int it = 0; it < nk; ++it) {
    const int cur = it & 1;
    if (it + 1 < nk) stage(cur ^ 1, (it + 1) << 6);   // prefetch flies under MFMA
    #pragma unroll
    for (int kk = 0; kk < 2; ++kk) {
      bf16x8v af[MR], bfv[NR];
      #pragma unroll
      for (int m = 0; m < MR; ++m)
        af[m] = *(const bf16x8v*)&sA[cur][(wm * WMt + m * 16 + lr) * 64 + kk * 32 + ko];
      #pragma unroll
      for (int n = 0; n < NR; ++n)
        bfv[n] = *(const bf16x8v*)&sB[cur][(wn * WNt + n * 16 + lr) * 64 + kk * 32 + ko];
      #pragma unroll
      for (int m = 0; m < MR; ++m)
        #pragma unroll
        for (int n = 0; n < NR; ++n)
          acc[m][n] = __builtin_amdgcn_mfma_f32_16x16x32_bf16(af[m], bfv[n], acc[m][n], 0, 0, 0);
    }
    __syncthreads();                       // drains prefetch + read-done fence
  }

  const int r0 = (lane >> 4) * 4;
  #pragma unroll
  for (int m = 0; m < MR; ++m) {
    #pragma unroll
    for (int n = 0; n < NR; ++n) {
      int gc = n0 + wn * WNt + n * 16 + lr;
      float bv = d.bias[gc];
      #pragma unroll
      for (int r = 0; r < 4; ++r) {
        int gr = m0 + wm * WMt + m * 16 + r0 + r;
        float v = acc[m][n][r] + bv;
        if (d.mode == 1)
          ((bf16*)d.C)[(size_t)gr * d.N + gc] = __float2bfloat16(v > 0.f ? v : 0.f);
        else
          ((float*)d.C)[(size_t)gr * d.N + gc] = v;
      }
    }
  }
}

// ---------------------------------------------------------------------------
// W2p GEMM (512x512, K=2048) + posterior epilogue, fused, atomics-free.
// 32 blocks: mb 0..7 (64 rows), nl 0..3 (cols nl*64..+63 of BOTH loc and raw).
// B strips: rows nl*64..+63 (loc) and 256+nl*64..+63 (raw) of W2pT.
// ---------------------------------------------------------------------------
__global__ __launch_bounds__(256)
void w2p_post(const bf16* __restrict__ hq, const bf16* __restrict__ W2pT,
              const float* __restrict__ b2p, const float* __restrict__ eps,
              float* __restrict__ o_mu, float* __restrict__ o_sd,
              float* __restrict__ o_st,
              const float* __restrict__ nt_next, const float* __restrict__ act_next,
              bf16* __restrict__ xcat, int make_xcat)
{
  constexpr int K = 2048, NK = K / 64;
  const int mb = blockIdx.x & 7, nl = blockIdx.x >> 3;
  const int m0 = mb * 64;

  __shared__ __align__(16) char smem[49152];
  bf16 (*sA)[64 * 64]  = (bf16(*)[64 * 64])smem;            // 2 x 8KB
  bf16 (*sB)[128 * 64] = (bf16(*)[128 * 64])(smem + 16384); // 2 x 16KB
  float* tile = (float*)smem;                               // 32KB reuse

  const int tid = threadIdx.x;
  const int lane = tid & 63;
  const int wid = tid >> 6;
  const int wm = wid >> 1, wn = wid & 1;
  const int lr = lane & 15;
  const int ko = (lane >> 4) * 8;

  const bf16* Abase = hq + (size_t)m0 * K;

  auto stage = [&](int buf, int k0) {
    #pragma unroll
    for (int i = 0; i < 2; ++i) {      // A: 64 rows
      int c = i * 256 + tid;
      gload_lds16(Abase + (size_t)(c >> 3) * K + k0 + (c & 7) * 8, &sA[buf][c * 8]);
    }
    #pragma unroll
    for (int i = 0; i < 4; ++i) {      // B: 128 rows (two strips of 64)
      int c = i * 256 + tid;
      int row = c >> 3;
      int grow = (row < 64) ? (nl * 64 + row) : (192 + nl * 64 + row); // 256+nl*64+(row-64)
      gload_lds16(W2pT + (size_t)grow * K + k0 + (c & 7) * 8, &sB[buf][c * 8]);
    }
  };

  f32x4 acc[2][4] = {};
  stage(0, 0);
  __syncthreads();
  for (int it = 0; it < NK; ++it) {
    const int cur = it & 1;
    if (it + 1 < NK) stage(cur ^ 1, (it + 1) << 6);
    #pragma unroll
    for (int kk = 0; kk < 2; ++kk) {
      bf16x8v af[2], bfv[4];
      #pragma unroll
      for (int m = 0; m < 2; ++m)
        af[m] = *(const bf16x8v*)&sA[cur][(wm * 32 + m * 16 + lr) * 64 + kk * 32 + ko];
      #pragma unroll
      for (int n = 0; n < 4; ++n)
        bfv[n] = *(const bf16x8v*)&sB[cur][(wn * 64 + n * 16 + lr) * 64 + kk * 32 + ko];
      #pragma unroll
      for (int m = 0; m < 2; ++m)
        #pragma unroll
        for (int n = 0; n < 4; ++n)
          acc[m][n] = __builtin_amdgcn_mfma_f32_16x16x32_bf16(af[m], bfv[n], acc[m][n], 0, 0, 0);
    }
    __syncthreads();
  }

  // dump acc -> f32 tile [64][128]
  const int r0 = (lane >> 4) * 4;
  #pragma unroll
  for (int m = 0; m < 2; ++m)
    #pragma unroll
    for (int n = 0; n < 4; ++n) {
      int tc = wn * 64 + n * 16 + lr;
      #pragma unroll
      for (int r = 0; r < 4; ++r)
        tile[(wm * 32 + m * 16 + r0 + r) * 128 + tc] = acc[m][n][r];
    }
  __syncthreads();

  // epilogue: cols 0..63 = loc(j), cols 64..127 = raw(j), j = nl*64+cc
  for (int e = tid; e < 4096; e += 256) {
    int rr = e >> 6, cc = e & 63;
    int b = m0 + rr;
    int j = nl * 64 + cc;
    float loc = tile[rr * 128 + cc] + b2p[j];
    float raw = tile[rr * 128 + 64 + cc] + b2p[256 + j];
    float sp = (raw > 20.f) ? raw : log1pf(__expf(raw));
    float scale = sp + 0.1f;
    float st = loc + scale * eps[(size_t)b * 256 + j];
    o_mu[(size_t)b * 256 + j] = loc;
    o_sd[(size_t)b * 256 + j] = scale;
    o_st[(size_t)b * 256 + j] = st;
    if (make_xcat) {
      xcat[(size_t)b * 320 + j] = __float2bfloat16(st * nt_next[b]);
      if (nl == 0)
        xcat[(size_t)b * 320 + 256 + cc] = __float2bfloat16(act_next[(size_t)b * 64 + cc]);
    }
  }
}

// ---------------------------------------------------------------------------
__global__ void transpose_cvt(const float* __restrict__ src, bf16* __restrict__ dst,
                              int K, int N)
{
  __shared__ float t[32][33];
  int n0 = blockIdx.x * 32, k0 = blockIdx.y * 32;
  int tx = threadIdx.x, ty = threadIdx.y;
  #pragma unroll
  for (int i = 0; i < 32; i += 8)
    t[ty + i][tx] = src[(size_t)(k0 + ty + i) * N + n0 + tx];
  __syncthreads();
  #pragma unroll
  for (int i = 0; i < 32; i += 8)
    dst[(size_t)(n0 + ty + i) * K + k0 + tx] = __float2bfloat16(t[tx][ty + i]);
}

__global__ void init_belief(const float* __restrict__ prev_belief,
                            float* __restrict__ bf32, bf16* __restrict__ bb16)
{
  int i = blockIdx.x * 256 + threadIdx.x;
  float v = prev_belief[i];
  bf32[i] = v;
  bb16[i] = __float2bfloat16(v);
}

__global__ void xcat0_kernel(const float* __restrict__ prev_state,
                             const float* __restrict__ nt0,
                             const float* __restrict__ act0,
                             bf16* __restrict__ xcat)
{
  int idx = blockIdx.x * 256 + threadIdx.x;
  if (idx >= BATCH * 320) return;
  int b = idx / 320;
  int c = idx - b * 320;
  float v;
  if (c < STATE) v = prev_state[b * STATE + c] * nt0[b];
  else           v = act0[b * ACTION + (c - STATE)];
  xcat[idx] = __float2bfloat16(v);
}

__device__ __forceinline__ float sigmoidf_(float x) { return 1.f / (1.f + __expf(-x)); }

__device__ __forceinline__ float gru1(float ir, float hr, float iz, float hz,
                                      float in_, float hn, float bo)
{
  float r = sigmoidf_(ir + hr);
  float z = sigmoidf_(iz + hz);
  float n = tanhf(in_ + r * hn);
  return (1.f - z) * n + z * bo;
}

__global__ void gru_ew(const float* __restrict__ gi, const float* __restrict__ gh,
                       float* __restrict__ belief, float* __restrict__ out_bel,
                       bf16* __restrict__ belief_b16, bf16* __restrict__ hqcat,
                       const float* __restrict__ obs_t)
{
  int i = blockIdx.x * 256 + threadIdx.x;   // float4 index over 512*2048/4
  int b = i >> 9;
  int c = (i & 511) * 4;
  size_t gb = (size_t)b * 6144;
  float4 ir = *(const float4*)&gi[gb + c];
  float4 iz = *(const float4*)&gi[gb + 2048 + c];
  float4 in_ = *(const float4*)&gi[gb + 4096 + c];
  float4 hr = *(const float4*)&gh[gb + c];
  float4 hz = *(const float4*)&gh[gb + 2048 + c];
  float4 hn = *(const float4*)&gh[gb + 4096 + c];
  float4 bo = *(const float4*)&belief[(size_t)b * 2048 + c];
  float4 nb;
  nb.x = gru1(ir.x, hr.x, iz.x, hz.x, in_.x, hn.x, bo.x);
  nb.y = gru1(ir.y, hr.y, iz.y, hz.y, in_.y, hn.y, bo.y);
  nb.z = gru1(ir.z, hr.z, iz.z, hz.z, in_.z, hn.z, bo.z);
  nb.w = gru1(ir.w, hr.w, iz.w, hz.w, in_.w, hn.w, bo.w);
  *(float4*)&belief[(size_t)b * 2048 + c] = nb;
  *(float4*)&out_bel[(size_t)b * 2048 + c] = nb;
  ushort4 u; u.x = bfb(nb.x); u.y = bfb(nb.y); u.z = bfb(nb.z); u.w = bfb(nb.w);
  *(ushort4*)&belief_b16[(size_t)b * 2048 + c] = u;
  *(ushort4*)&hqcat[(size_t)b * 3072 + c] = u;
  if ((i & 511) < 256) {
    float4 ov = *(const float4*)&obs_t[(size_t)b * 1024 + c];
    ushort4 uo; uo.x = bfb(ov.x); uo.y = bfb(ov.y); uo.z = bfb(ov.z); uo.w = bfb(ov.w);
    *(ushort4*)&hqcat[(size_t)b * 3072 + 2048 + c] = uo;
  }
}

__global__ void cvt_f32_bf16(const float* __restrict__ src, bf16* __restrict__ dst)
{
  int i = blockIdx.x * 256 + threadIdx.x;
  float4 v = *(const float4*)&src[i * 4];
  ushort4 u; u.x = bfb(v.x); u.y = bfb(v.y); u.z = bfb(v.z); u.w = bfb(v.w);
  *(ushort4*)&dst[i * 4] = u;
}

__global__ void prior_ew(const float* __restrict__ yp, const float* __restrict__ eps,
                         float* __restrict__ o_mu, float* __restrict__ o_sd,
                         float* __restrict__ o_st)
{
  int idx = blockIdx.x * 256 + threadIdx.x;   // 4096*256
  int r = idx >> 8;
  int j = idx & 255;
  float loc = yp[(size_t)r * 512 + j];
  float raw = yp[(size_t)r * 512 + 256 + j];
  float sp = (raw > 20.f) ? raw : log1pf(__expf(raw));
  float scale = sp + 0.1f;
  o_mu[idx] = loc;
  o_sd[idx] = scale;
  o_st[idx] = loc + scale * eps[idx];
}

// ---------------------------------------------------------------------------
extern "C" void kernel_launch(void* const* d_in, const int* in_sizes, int n_in,
                              void* d_out, int out_size, void* d_ws, size_t ws_size,
                              hipStream_t stream)
{
  (void)in_sizes; (void)n_in; (void)out_size; (void)ws_size;
  const float* prev_state = (const float*)d_in[0];
  const float* actions    = (const float*)d_in[1];
  const float* prev_belief= (const float*)d_in[2];
  const float* obs_emb    = (const float*)d_in[3];
  const float* nonterm    = (const float*)d_in[4];
  const float* W_embed    = (const float*)d_in[5];
  const float* b_embed    = (const float*)d_in[6];
  const float* Wi         = (const float*)d_in[7];
  const float* bi         = (const float*)d_in[8];
  const float* Wh         = (const float*)d_in[9];
  const float* bh         = (const float*)d_in[10];
  const float* W1         = (const float*)d_in[11];
  const float* b1         = (const float*)d_in[12];
  const float* W2         = (const float*)d_in[13];
  const float* b2         = (const float*)d_in[14];
  const float* W1p        = (const float*)d_in[15];
  const float* b1p        = (const float*)d_in[16];
  const float* W2p        = (const float*)d_in[17];
  const float* b2p        = (const float*)d_in[18];
  const float* eps_p      = (const float*)d_in[19];
  const float* eps_q      = (const float*)d_in[20];
  float* out = (float*)d_out;

  char* ws = (char*)d_ws;
  size_t off = 0;
  auto alloc = [&](size_t bytes) -> char* {
    char* p = ws + off;
    off = (off + bytes + 255) & ~(size_t)255;
    return p;
  };
  bf16* WembT = (bf16*)alloc((size_t)2048 * 320 * 2);
  bf16* WiT   = (bf16*)alloc((size_t)6144 * 2048 * 2);
  bf16* WhT   = (bf16*)alloc((size_t)6144 * 2048 * 2);
  bf16* W1T   = (bf16*)alloc((size_t)2048 * 2048 * 2);
  bf16* W2T   = (bf16*)alloc((size_t)512 * 2048 * 2);
  bf16* W1pT  = (bf16*)alloc((size_t)2048 * 3072 * 2);
  bf16* W2pT  = (bf16*)alloc((size_t)512 * 2048 * 2);
  float* belief_f32 = (float*)alloc((size_t)BATCH * BELIEF * 4);
  bf16*  belief_b16 = (bf16*)alloc((size_t)BATCH * BELIEF * 2);
  bf16*  xcat       = (bf16*)alloc((size_t)BATCH * 320 * 2);
  bf16*  hidden     = (bf16*)alloc((size_t)BATCH * BELIEF * 2);
  float* gi         = (float*)alloc((size_t)BATCH * 3 * BELIEF * 4);
  float* gh         = (float*)alloc((size_t)BATCH * 3 * BELIEF * 4);
  bf16*  hqcat      = (bf16*)alloc((size_t)BATCH * 3072 * 2);
  bf16*  hq         = (bf16*)alloc((size_t)BATCH * HIDDEN * 2);
  bf16*  belA       = (bf16*)alloc((size_t)4096 * BELIEF * 2);
  bf16*  hp         = (bf16*)alloc((size_t)4096 * HIDDEN * 2);
  float* yp         = (float*)alloc((size_t)4096 * 512 * 4);

  auto mk = [](const bf16* A, const bf16* B, const float* bias, void* C,
               int M, int N, int K, int mode, int BM, int BN) {
    GDesc g; g.A = A; g.B = B; g.bias = bias; g.C = C;
    g.M = M; g.N = N; g.K = K; g.mode = mode;
    g.nb = (M / BM) * (N / BN);
    return g;
  };
  GDesc dz{}; dz.nb = 0;

  dim3 tb(32, 8);
  transpose_cvt<<<dim3(2048/32, 320/32),  tb, 0, stream>>>(W_embed, WembT, 320, 2048);
  transpose_cvt<<<dim3(6144/32, 2048/32), tb, 0, stream>>>(Wi, WiT, 2048, 6144);
  transpose_cvt<<<dim3(6144/32, 2048/32), tb, 0, stream>>>(Wh, WhT, 2048, 6144);
  transpose_cvt<<<dim3(2048/32, 2048/32), tb, 0, stream>>>(W1, W1T, 2048, 2048);
  transpose_cvt<<<dim3(512/32, 2048/32),  tb, 0, stream>>>(W2, W2T, 2048, 512);
  transpose_cvt<<<dim3(2048/32, 3072/32), tb, 0, stream>>>(W1p, W1pT, 3072, 2048);
  transpose_cvt<<<dim3(512/32, 2048/32),  tb, 0, stream>>>(W2p, W2pT, 2048, 512);

  init_belief<<<(BATCH * BELIEF) / 256, 256, 0, stream>>>(prev_belief, belief_f32, belief_b16);
  xcat0_kernel<<<(BATCH * 320 + 255) / 256, 256, 0, stream>>>(prev_state, nonterm, actions, xcat);

  { // hidden_0 = relu(xcat0 @ W_embed)  [512,2048] K=320 — 256 blocks
    GDesc e = mk(xcat, WembT, b_embed, hidden, 512, 2048, 320, 1, 64, 64);
    gemm2<64,64><<<e.nb, 256, 0, stream>>>(e, dz);
  }

  for (int t = 0; t < TM1; ++t) {
    // gi = hidden @ Wi + bi ; gh = belief @ Wh + bh   [512,6144] K=2048 — 512 blocks
    GDesc a0 = mk(hidden, WiT, bi, gi, 512, 6144, 2048, 0, 128, 96);
    GDesc a1 = mk(belief_b16, WhT, bh, gh, 512, 6144, 2048, 0, 128, 96);
    gemm2<128,96><<<a0.nb + a1.nb, 256, 0, stream>>>(a0, a1);

    gru_ew<<<1024, 256, 0, stream>>>(
        gi, gh, belief_f32,
        out + OUT_BEL + (size_t)t * BATCH * BELIEF,
        belief_b16, hqcat, obs_emb + (size_t)t * BATCH * EMB);

    // hq = relu(hqcat @ W1p + b1p)   [512,2048] K=3072 — 256 blocks
    GDesc b0 = mk(hqcat, W1pT, b1p, hq, 512, 2048, 3072, 1, 64, 64);
    gemm2<64,64><<<b0.nb, 256, 0, stream>>>(b0, dz);

    // fused: yq = hq @ W2p + b2p -> softplus/rsample -> outputs + next xcat
    int tn = (t < TM1 - 1) ? t + 1 : t;
    w2p_post<<<32, 256, 0, stream>>>(
        hq, W2pT, b2p,
        eps_q + (size_t)t * BATCH * STATE,
        out + OUT_QMU + (size_t)t * BATCH * STATE,
        out + OUT_QSD + (size_t)t * BATCH * STATE,
        out + OUT_QST + (size_t)t * BATCH * STATE,
        nonterm + (size_t)tn * BATCH,
        actions + (size_t)tn * BATCH * ACTION,
        xcat, (t < TM1 - 1) ? 1 : 0);

    if (t < TM1 - 1) { // hidden_{t+1} = relu(xcat @ W_embed)
      GDesc e = mk(xcat, WembT, b_embed, hidden, 512, 2048, 320, 1, 64, 64);
      gemm2<64,64><<<e.nb, 256, 0, stream>>>(e, dz);
    }
  }

  // batched prior over all T*B rows, 8 chunks of 4096 rows
  for (int c = 0; c < 8; ++c) {
    const float* belsrc = out + OUT_BEL + (size_t)c * 4096 * BELIEF;
    cvt_f32_bf16<<<(4096 * BELIEF / 4) / 256, 256, 0, stream>>>(belsrc, belA);
    GDesc p1 = mk(belA, W1T, b1, hp, 4096, 2048, 2048, 1, 128, 128);
    gemm2<128,128><<<p1.nb, 256, 0, stream>>>(p1, dz);
    GDesc p2 = mk(hp, W2T, b2, yp, 4096, 512, 2048, 0, 64, 64);
    gemm2<64,64><<<p2.nb, 256, 0, stream>>>(p2, dz);
    prior_ew<<<4096, 256, 0, stream>>>(
        yp, eps_p + (size_t)c * 4096 * STATE,
        out + OUT_PMU + (size_t)c * 4096 * STATE,
        out + OUT_PSD + (size_t)c * 4096 * STATE,
        out + OUT_PST + (size_t)c * 4096 * STATE);
  }
}